// Round 4
// baseline (333.833 us; speedup 1.0000x reference)
//
#include <hip/hip_runtime.h>
#include <cstdint>

#define TOPK 2000
#define NMS_THR 0.5f
#define NCLS 21
#define HSHIFT 14
#define HBINS (1u << 18)
#define CAND_CAP 4096
#define TPAD 2048

typedef unsigned long long u64;
typedef unsigned int u32;

// IoU exactly as reference get_iou. contract(off) to match numpy rounding.
__device__ __forceinline__ float iou_pair(float ax1, float ay1, float ax2, float ay2, float aarea,
                                          float bx1, float by1, float bx2, float by2, float barea) {
#pragma clang fp contract(off)
    float ltx = fmaxf(ax1, bx1), lty = fmaxf(ay1, by1);
    float rbx = fminf(ax2, bx2), rby = fminf(ay2, by2);
    float wx = fmaxf(rbx - ltx, 0.f), wy = fmaxf(rby - lty, 0.f);
    float inter = wx * wy;
    return inter / (aarea + barea - inter);
}

__global__ void k_zero(u32* __restrict__ hist, u32* __restrict__ meta) {
    int i = blockIdx.x * 256 + threadIdx.x;
    ((uint4*)hist)[i] = make_uint4(0u, 0u, 0u, 0u);
    if (i < 64) meta[i] = 0u;
}

// Per-proposal: softmax score+cls, decode selected-class box (clamped),
// score bits + histogram, GT IoU argmax (4x unrolled, first-max tree),
// encode reg targets -> out rows 2000+.
__global__ __launch_bounds__(256) void k_main(
    const float* __restrict__ prop, const float* __restrict__ btp,
    const float* __restrict__ cls, const float* __restrict__ gt,
    const int* __restrict__ hptr, const int* __restrict__ wptr,
    float* __restrict__ out, float4* __restrict__ box_per,
    u32* __restrict__ score_bits, u32* __restrict__ hist,
    int N, int G) {
#pragma clang fp contract(off)
    __shared__ float4 sgt[256];
    __shared__ float sga[256];
    __shared__ float scls[256 * NCLS];
    int tid = threadIdx.x;
    for (int g = tid; g < G; g += 256) {
        float4 gb = ((const float4*)gt)[g];
        sgt[g] = gb;
        sga[g] = (gb.z - gb.x) * (gb.w - gb.y);
    }
    size_t base = (size_t)blockIdx.x * 256 * NCLS;
    size_t total = (size_t)N * NCLS;
    int cnt = (int)((total > base) ? ((total - base > (size_t)(256 * NCLS)) ? (size_t)(256 * NCLS)
                                                                            : (total - base))
                                   : (size_t)0);
    if (cnt == 256 * NCLS) {
        const float4* src = (const float4*)(cls + base);
        for (int u = tid; u < 256 * NCLS / 4; u += 256) ((float4*)scls)[u] = src[u];
    } else {
        for (int u = tid; u < cnt; u += 256) scls[u] = cls[base + u];
    }
    __syncthreads();

    int i = blockIdx.x * 256 + tid;
    if (i >= N) return;

    float W = (float)wptr[0], H = (float)hptr[0];
    float4 p = ((const float4*)prop)[i];
    float pw = p.z - p.x, ph = p.w - p.y;
    float pcx = p.x + 0.5f * pw, pcy = p.y + 0.5f * ph;

    const float* s = &scls[tid * NCLS];
    float m = s[0];
#pragma unroll
    for (int c = 1; c < NCLS; ++c) m = fmaxf(m, s[c]);
    float e[NCLS];
    float Z = 0.f;
#pragma unroll
    for (int c = 0; c < NCLS; ++c) {
        e[c] = expf(s[c] - m);
        Z += e[c];
    }
    float best = -1.f;
    int bc = 1;
#pragma unroll
    for (int c = 1; c < NCLS; ++c) {
        float pr = e[c] / Z;
        if (pr > best) { best = pr; bc = c; }
    }

    float4 t = ((const float4*)btp)[(size_t)i * NCLS + bc];
    float qcx = t.x * pw + pcx, qcy = t.y * ph + pcy;
    float qw = expf(t.z) * pw, qh = expf(t.w) * ph;
    float bx1 = fminf(fmaxf(qcx - 0.5f * qw, 0.f), W);
    float by1 = fminf(fmaxf(qcy - 0.5f * qh, 0.f), H);
    float bx2 = fminf(fmaxf(qcx + 0.5f * qw, 0.f), W);
    float by2 = fminf(fmaxf(qcy + 0.5f * qh, 0.f), H);
    box_per[i] = make_float4(bx1, by1, bx2, by2);

    u32 b = __float_as_uint(best);
    score_bits[i] = b;

    // GT IoU argmax, 4x unrolled with first-max combine tree (left preference,
    // strict > ) -- result bit-identical to the sequential scan.
    float parea = pw * ph;
    float bestiou = -1.f;
    int bi = 0;
    int g = 0;
    for (; g + 4 <= G; g += 4) {
        float4 g0 = sgt[g], g1 = sgt[g + 1], g2 = sgt[g + 2], g3 = sgt[g + 3];
        float v0 = iou_pair(g0.x, g0.y, g0.z, g0.w, sga[g], p.x, p.y, p.z, p.w, parea);
        float v1 = iou_pair(g1.x, g1.y, g1.z, g1.w, sga[g + 1], p.x, p.y, p.z, p.w, parea);
        float v2 = iou_pair(g2.x, g2.y, g2.z, g2.w, sga[g + 2], p.x, p.y, p.z, p.w, parea);
        float v3 = iou_pair(g3.x, g3.y, g3.z, g3.w, sga[g + 3], p.x, p.y, p.z, p.w, parea);
        float va = v0; int ia = g;
        if (v1 > va) { va = v1; ia = g + 1; }
        float vb = v2; int ib = g + 2;
        if (v3 > vb) { vb = v3; ib = g + 3; }
        if (vb > va) { va = vb; ia = ib; }
        if (va > bestiou) { bestiou = va; bi = ia; }
    }
    for (; g < G; ++g) {
        float4 gb = sgt[g];
        float v = iou_pair(gb.x, gb.y, gb.z, gb.w, sga[g], p.x, p.y, p.z, p.w, parea);
        if (v > bestiou) { bestiou = v; bi = g; }
    }
    float4 mg = sgt[bi];
    float gw = mg.z - mg.x, gh = mg.w - mg.y;
    float gcx = mg.x + 0.5f * gw, gcy = mg.y + 0.5f * gh;
    float4 rt = make_float4((gcx - pcx) / pw, (gcy - pcy) / ph, logf(gw / pw), logf(gh / ph));
    ((float4*)out)[TOPK + i] = rt;

    atomicAdd(&hist[b >> HSHIFT], 1u);
}

// 1024 blocks x 256: coalesced per-256-bin chunk sums.
__global__ __launch_bounds__(256) void k_hsum(const u32* __restrict__ hist,
                                              u32* __restrict__ csum) {
    int b = blockIdx.x, t = threadIdx.x;
    u32 v = hist[(size_t)b * 256 + t];
#pragma unroll
    for (int o = 32; o; o >>= 1) v += __shfl_xor(v, o);
    __shared__ u32 ps[4];
    if ((t & 63) == 0) ps[t >> 6] = v;
    __syncthreads();
    if (t == 0) csum[b] = ps[0] + ps[1] + ps[2] + ps[3];
}

// One small block: suffix-scan chunk sums, then the winning 256-bin chunk.
__global__ __launch_bounds__(1024) void k_scan2(const u32* __restrict__ csum,
                                                const u32* __restrict__ hist,
                                                u32* __restrict__ meta) {
    __shared__ u32 S[1024];
    __shared__ u32 sh_tc, sh_E;
    int t = threadIdx.x;
    u32 acc = csum[t];
    S[t] = acc;
    __syncthreads();
    for (int off = 1; off < 1024; off <<= 1) {
        u32 v = (t + off < 1024) ? S[t + off] : 0u;
        __syncthreads();
        S[t] += v;
        __syncthreads();
    }
    u32 suff = S[t];
    u32 E = suff - acc;
    if (suff >= TOPK && E < TOPK) { sh_tc = (u32)t; sh_E = E; }
    __syncthreads();
    u32 tc = sh_tc, E0 = sh_E;
    u32 h = (t < 256) ? hist[(size_t)tc * 256 + t] : 0u;
    __syncthreads();
    S[t] = (t < 256) ? h : 0u;
    __syncthreads();
    for (int off = 1; off < 256; off <<= 1) {
        u32 v = (t + off < 1024) ? S[t + off] : 0u;
        __syncthreads();
        S[t] += v;
        __syncthreads();
    }
    if (t < 256) {
        u32 tot = E0 + S[t];
        if (tot >= TOPK && (tot - h) < TOPK) meta[0] = tc * 256u + (u32)t;
    }
}

__global__ __launch_bounds__(256) void k_compact(const u32* __restrict__ score_bits,
                                                 const u32* __restrict__ meta, u32* __restrict__ cnt,
                                                 u64* __restrict__ keys, int N) {
    int i = blockIdx.x * 256 + threadIdx.x;
    if (i >= N) return;
    u32 b = score_bits[i];
    if ((b >> HSHIFT) >= meta[0]) {
        u32 pos = atomicAdd(cnt, 1u);
        if (pos < CAND_CAP) keys[pos] = ((u64)b << 32) | (u32)(~(u32)i);
    }
}

// Rank-sort, 16 blocks. Tile keys 64-at-a-time; broadcast via v_readlane.
// Keys unique -> ranks form a permutation; exact lax.top_k order.
__global__ __launch_bounds__(256) void k_rank(const u64* __restrict__ keys,
                                              const u32* __restrict__ meta,
                                              const float4* __restrict__ box_per,
                                              float4* __restrict__ topbox) {
    __shared__ u64 sk[CAND_CAP];
    int t = threadIdx.x;
    u32 M = meta[1];
    if (M > CAND_CAP) M = CAND_CAP;
    u32 Mp = (M + 63u) & ~63u;
    for (int u = t; u < (int)Mp; u += 256) sk[u] = (u < (int)M) ? keys[u] : 0ull;
    __syncthreads();
    int idx = blockIdx.x * 256 + t;
    u64 k = (idx < (int)M) ? sk[idx] : ~0ull;
    u32 r = 0;
    int lane = t & 63;
    for (int j0 = 0; j0 < (int)Mp; j0 += 64) {
        u64 tv = sk[j0 + lane];
        u32 tlo = (u32)tv, thi = (u32)(tv >> 32);
#pragma unroll
        for (int l = 0; l < 64; ++l) {
            u64 kj = ((u64)(u32)__builtin_amdgcn_readlane(thi, l) << 32) |
                     (u64)(u32)__builtin_amdgcn_readlane(tlo, l);
            r += (kj > k) ? 1u : 0u;
        }
    }
    if (idx < (int)M && r < TOPK) topbox[r] = box_per[~(u32)(k & 0xffffffffull)];
}

// Suppression mask, ROW-major: mask[i*32+w] bit jj set iff j=w*64+jj>i, j<TOPK,
// iou>thr. w is block-uniform (topbox[j] broadcast loads).
__global__ __launch_bounds__(256) void k_mask(const float4* __restrict__ topbox,
                                              u64* __restrict__ mask) {
#pragma clang fp contract(off)
    int gid = blockIdx.x * 256 + threadIdx.x;  // 32 * TPAD threads
    int w = gid >> 11, i = gid & (TPAD - 1);
    u64 m = 0;
    int j0 = w << 6;
    if (i < TOPK && j0 + 63 > i) {
        float4 a = topbox[i];
        float aarea = (a.z - a.x) * (a.w - a.y);
        for (int jj = 0; jj < 64; ++jj) {
            int j = j0 + jj;
            if (j < TOPK && j > i) {
                float4 b = topbox[j];
                float barea = (b.z - b.x) * (b.w - b.y);
                float v = iou_pair(a.x, a.y, a.z, a.w, aarea, b.x, b.y, b.z, b.w, barea);
                if (v > NMS_THR) m |= (1ull << jj);
            }
        }
    }
    mask[(size_t)i * 32 + w] = m;
}

// Greedy NMS. Producer/consumer: waves 1-3 stage the next 64-row chunk
// (16 KB) global->LDS while wave 0 runs the serial recurrence from LDS with
// an 8-deep register ring (16 VGPRs -- small enough to never spill; R2/R3's
// 64/128-VGPR arrays spilled to scratch and cost ~100us). Uniform barriers.
__global__ __launch_bounds__(256) void k_nms(const u64* __restrict__ mask,
                                             const float4* __restrict__ topbox,
                                             float* __restrict__ out) {
    __shared__ u64 sm[2][64 * 32];  // 2 x 16 KB double buffer
    __shared__ u64 srem[32];
    int t = threadIdx.x;
    int lane = t & 63;
    u32 lw = (u32)(lane & 31);
    u32 rlo = 0, rhi = 0;  // lane w of wave 0 holds removed word w

    for (int u = t; u < 2048; u += 256) sm[0][u] = mask[u];  // stage chunk 0
    __syncthreads();

    for (int c = 0; c < 32; ++c) {
        if (t >= 64) {
            if (c + 1 < 32) {
                const u64* __restrict__ src = mask + (size_t)(c + 1) * 2048;
                u64* __restrict__ dst = sm[(c + 1) & 1];
                for (int u = t - 64; u < 2048; u += 192) dst[u] = src[u];
            }
        } else {
            const u64* __restrict__ buf = sm[c & 1];
            u64 ring[8];
#pragma unroll
            for (int p = 0; p < 8; ++p) ring[p] = buf[p * 32 + lw];
#pragma unroll
            for (int l = 0; l < 64; ++l) {
                u64 row = ring[l & 7];
                if (l < 56) ring[l & 7] = buf[(l + 8) * 32 + lw];
                u32 h = (l < 32) ? (u32)__builtin_amdgcn_readlane(rlo, c)
                                 : (u32)__builtin_amdgcn_readlane(rhi, c);
                u32 keep = ((h >> (l & 31)) & 1u) ^ 1u;
                u32 mk = 0u - keep;
                rlo |= (u32)row & mk;
                rhi |= (u32)(row >> 32) & mk;
            }
        }
        __syncthreads();
    }
    if (t < 32) srem[t] = ((u64)rhi << 32) | rlo;
    __syncthreads();
    for (int r = t; r < TOPK; r += 256) {
        bool sup = (srem[r >> 6] >> (r & 63)) & 1ull;
        float4 b = topbox[r];
        ((float4*)out)[r] = sup ? make_float4(0.f, 0.f, 0.f, 0.f) : b;
    }
}

extern "C" void kernel_launch(void* const* d_in, const int* in_sizes, int n_in,
                              void* d_out, int out_size, void* d_ws, size_t ws_size,
                              hipStream_t stream) {
    const float* prop = (const float*)d_in[0];
    const float* btp = (const float*)d_in[1];
    const float* cls = (const float*)d_in[2];
    const float* gt = (const float*)d_in[3];
    const int* hptr = (const int*)d_in[4];
    const int* wptr = (const int*)d_in[5];
    float* out = (float*)d_out;
    int N = in_sizes[0] / 4;
    int G = in_sizes[3] / 4;
    if (G > 256) G = 256;

    char* ws = (char*)d_ws;
    size_t o = 0;
    u32* hist = (u32*)(ws + o);       o += (size_t)HBINS * 4;
    u32* csum = (u32*)(ws + o);       o += 1024 * 4;
    u32* meta = (u32*)(ws + o);       o += 256;
    u32* score_bits = (u32*)(ws + o); o += (((size_t)N * 4 + 255) & ~(size_t)255);
    u64* keys = (u64*)(ws + o);       o += (size_t)CAND_CAP * 8;
    float4* box_per = (float4*)(ws + o); o += (size_t)N * 16;
    float4* topbox = (float4*)(ws + o);  o += (size_t)TPAD * 16;
    u64* mask = (u64*)(ws + o);       o += (size_t)TPAD * 32 * 8;
    (void)o; (void)ws_size; (void)n_in; (void)out_size;

    int nb = (N + 255) / 256;
    k_zero<<<HBINS / 4 / 256, 256, 0, stream>>>(hist, meta);
    k_main<<<nb, 256, 0, stream>>>(prop, btp, cls, gt, hptr, wptr, out, box_per, score_bits,
                                   hist, N, G);
    k_hsum<<<1024, 256, 0, stream>>>(hist, csum);
    k_scan2<<<1, 1024, 0, stream>>>(csum, hist, meta);
    k_compact<<<nb, 256, 0, stream>>>(score_bits, meta, meta + 1, keys, N);
    k_rank<<<CAND_CAP / 256, 256, 0, stream>>>(keys, meta, box_per, topbox);
    k_mask<<<(32 * TPAD) / 256, 256, 0, stream>>>(topbox, mask);
    k_nms<<<1, 256, 0, stream>>>(mask, topbox, out);
}

// Round 5
// 321.153 us; speedup vs baseline: 1.0395x; 1.0395x over previous
//
#include <hip/hip_runtime.h>
#include <cstdint>

#define TOPK 2000
#define NMS_THR 0.5f
#define NCLS 21
#define HSHIFT 14
#define HBINS (1u << 18)
#define CAND_CAP 4096
#define TPAD 2048

typedef unsigned long long u64;
typedef unsigned int u32;

// IoU exactly as reference get_iou. contract(off) to match numpy rounding.
__device__ __forceinline__ float iou_pair(float ax1, float ay1, float ax2, float ay2, float aarea,
                                          float bx1, float by1, float bx2, float by2, float barea) {
#pragma clang fp contract(off)
    float ltx = fmaxf(ax1, bx1), lty = fmaxf(ay1, by1);
    float rbx = fminf(ax2, bx2), rby = fminf(ay2, by2);
    float wx = fmaxf(rbx - ltx, 0.f), wy = fmaxf(rby - lty, 0.f);
    float inter = wx * wy;
    return inter / (aarea + barea - inter);
}

__global__ void k_zero(u32* __restrict__ hist, u32* __restrict__ meta) {
    int i = blockIdx.x * 256 + threadIdx.x;
    ((uint4*)hist)[i] = make_uint4(0u, 0u, 0u, 0u);
    if (i < 64) meta[i] = 0u;
}

// Per-proposal: softmax score+cls, decode selected-class box (clamped),
// score bits + histogram, GT IoU argmax (4x unrolled, first-max tree),
// encode reg targets -> out rows 2000+.
// No cls LDS staging: per-lane contiguous 84B row reads; LDS only holds GT
// boxes (2.5KB) so occupancy is VGPR-bound (~6 waves/SIMD), hiding the btp
// gather latency that dominated at 18% occupancy.
__global__ __launch_bounds__(256) void k_main(
    const float* __restrict__ prop, const float* __restrict__ btp,
    const float* __restrict__ cls, const float* __restrict__ gt,
    const int* __restrict__ hptr, const int* __restrict__ wptr,
    float* __restrict__ out, float4* __restrict__ box_per,
    u32* __restrict__ score_bits, u32* __restrict__ hist,
    int N, int G) {
#pragma clang fp contract(off)
    __shared__ float4 sgt[256];
    __shared__ float sga[256];
    int tid = threadIdx.x;
    for (int g = tid; g < G; g += 256) {
        float4 gb = ((const float4*)gt)[g];
        sgt[g] = gb;
        sga[g] = (gb.z - gb.x) * (gb.w - gb.y);
    }
    __syncthreads();

    int i = blockIdx.x * 256 + tid;
    if (i >= N) return;

    float W = (float)wptr[0], H = (float)hptr[0];
    float4 p = ((const float4*)prop)[i];
    float pw = p.z - p.x, ph = p.w - p.y;
    float pcx = p.x + 0.5f * pw, pcy = p.y + 0.5f * ph;

    float s[NCLS];
    const float* crow = cls + (size_t)i * NCLS;
#pragma unroll
    for (int c = 0; c < NCLS; ++c) s[c] = crow[c];

    float m = s[0];
#pragma unroll
    for (int c = 1; c < NCLS; ++c) m = fmaxf(m, s[c]);
    float e[NCLS];
    float Z = 0.f;
#pragma unroll
    for (int c = 0; c < NCLS; ++c) {
        e[c] = expf(s[c] - m);
        Z += e[c];
    }
    float best = -1.f;
    int bc = 1;
#pragma unroll
    for (int c = 1; c < NCLS; ++c) {
        float pr = e[c] / Z;
        if (pr > best) { best = pr; bc = c; }
    }

    float4 t = ((const float4*)btp)[(size_t)i * NCLS + bc];
    float qcx = t.x * pw + pcx, qcy = t.y * ph + pcy;
    float qw = expf(t.z) * pw, qh = expf(t.w) * ph;
    float bx1 = fminf(fmaxf(qcx - 0.5f * qw, 0.f), W);
    float by1 = fminf(fmaxf(qcy - 0.5f * qh, 0.f), H);
    float bx2 = fminf(fmaxf(qcx + 0.5f * qw, 0.f), W);
    float by2 = fminf(fmaxf(qcy + 0.5f * qh, 0.f), H);
    box_per[i] = make_float4(bx1, by1, bx2, by2);

    u32 b = __float_as_uint(best);
    score_bits[i] = b;

    // GT IoU argmax, 4x unrolled with first-max combine tree (left preference,
    // strict >) -- result bit-identical to the sequential scan.
    float parea = pw * ph;
    float bestiou = -1.f;
    int bi = 0;
    int g = 0;
    for (; g + 4 <= G; g += 4) {
        float4 g0 = sgt[g], g1 = sgt[g + 1], g2 = sgt[g + 2], g3 = sgt[g + 3];
        float v0 = iou_pair(g0.x, g0.y, g0.z, g0.w, sga[g], p.x, p.y, p.z, p.w, parea);
        float v1 = iou_pair(g1.x, g1.y, g1.z, g1.w, sga[g + 1], p.x, p.y, p.z, p.w, parea);
        float v2 = iou_pair(g2.x, g2.y, g2.z, g2.w, sga[g + 2], p.x, p.y, p.z, p.w, parea);
        float v3 = iou_pair(g3.x, g3.y, g3.z, g3.w, sga[g + 3], p.x, p.y, p.z, p.w, parea);
        float va = v0; int ia = g;
        if (v1 > va) { va = v1; ia = g + 1; }
        float vb = v2; int ib = g + 2;
        if (v3 > vb) { vb = v3; ib = g + 3; }
        if (vb > va) { va = vb; ia = ib; }
        if (va > bestiou) { bestiou = va; bi = ia; }
    }
    for (; g < G; ++g) {
        float4 gb = sgt[g];
        float v = iou_pair(gb.x, gb.y, gb.z, gb.w, sga[g], p.x, p.y, p.z, p.w, parea);
        if (v > bestiou) { bestiou = v; bi = g; }
    }
    float4 mg = sgt[bi];
    float gw = mg.z - mg.x, gh = mg.w - mg.y;
    float gcx = mg.x + 0.5f * gw, gcy = mg.y + 0.5f * gh;
    float4 rt = make_float4((gcx - pcx) / pw, (gcy - pcy) / ph, logf(gw / pw), logf(gh / ph));
    ((float4*)out)[TOPK + i] = rt;

    atomicAdd(&hist[b >> HSHIFT], 1u);
}

// 1024 blocks x 256: coalesced per-256-bin chunk sums.
__global__ __launch_bounds__(256) void k_hsum(const u32* __restrict__ hist,
                                              u32* __restrict__ csum) {
    int b = blockIdx.x, t = threadIdx.x;
    u32 v = hist[(size_t)b * 256 + t];
#pragma unroll
    for (int o = 32; o; o >>= 1) v += __shfl_xor(v, o);
    __shared__ u32 ps[4];
    if ((t & 63) == 0) ps[t >> 6] = v;
    __syncthreads();
    if (t == 0) csum[b] = ps[0] + ps[1] + ps[2] + ps[3];
}

// One small block: suffix-scan chunk sums, then the winning 256-bin chunk.
__global__ __launch_bounds__(1024) void k_scan2(const u32* __restrict__ csum,
                                                const u32* __restrict__ hist,
                                                u32* __restrict__ meta) {
    __shared__ u32 S[1024];
    __shared__ u32 sh_tc, sh_E;
    int t = threadIdx.x;
    u32 acc = csum[t];
    S[t] = acc;
    __syncthreads();
    for (int off = 1; off < 1024; off <<= 1) {
        u32 v = (t + off < 1024) ? S[t + off] : 0u;
        __syncthreads();
        S[t] += v;
        __syncthreads();
    }
    u32 suff = S[t];
    u32 E = suff - acc;
    if (suff >= TOPK && E < TOPK) { sh_tc = (u32)t; sh_E = E; }
    __syncthreads();
    u32 tc = sh_tc, E0 = sh_E;
    u32 h = (t < 256) ? hist[(size_t)tc * 256 + t] : 0u;
    __syncthreads();
    S[t] = (t < 256) ? h : 0u;
    __syncthreads();
    for (int off = 1; off < 256; off <<= 1) {
        u32 v = (t + off < 1024) ? S[t + off] : 0u;
        __syncthreads();
        S[t] += v;
        __syncthreads();
    }
    if (t < 256) {
        u32 tot = E0 + S[t];
        if (tot >= TOPK && (tot - h) < TOPK) meta[0] = tc * 256u + (u32)t;
    }
}

__global__ __launch_bounds__(256) void k_compact(const u32* __restrict__ score_bits,
                                                 const u32* __restrict__ meta, u32* __restrict__ cnt,
                                                 u64* __restrict__ keys, int N) {
    int i = blockIdx.x * 256 + threadIdx.x;
    if (i >= N) return;
    u32 b = score_bits[i];
    if ((b >> HSHIFT) >= meta[0]) {
        u32 pos = atomicAdd(cnt, 1u);
        if (pos < CAND_CAP) keys[pos] = ((u64)b << 32) | (u32)(~(u32)i);
    }
}

// Rank-sort, 16 blocks. Tile keys 64-at-a-time; broadcast via v_readlane.
// Keys unique -> ranks form a permutation; exact lax.top_k order.
__global__ __launch_bounds__(256) void k_rank(const u64* __restrict__ keys,
                                              const u32* __restrict__ meta,
                                              const float4* __restrict__ box_per,
                                              float4* __restrict__ topbox) {
    __shared__ u64 sk[CAND_CAP];
    int t = threadIdx.x;
    u32 M = meta[1];
    if (M > CAND_CAP) M = CAND_CAP;
    u32 Mp = (M + 63u) & ~63u;
    for (int u = t; u < (int)Mp; u += 256) sk[u] = (u < (int)M) ? keys[u] : 0ull;
    __syncthreads();
    int idx = blockIdx.x * 256 + t;
    u64 k = (idx < (int)M) ? sk[idx] : ~0ull;
    u32 r = 0;
    int lane = t & 63;
    for (int j0 = 0; j0 < (int)Mp; j0 += 64) {
        u64 tv = sk[j0 + lane];
        u32 tlo = (u32)tv, thi = (u32)(tv >> 32);
#pragma unroll
        for (int l = 0; l < 64; ++l) {
            u64 kj = ((u64)(u32)__builtin_amdgcn_readlane(thi, l) << 32) |
                     (u64)(u32)__builtin_amdgcn_readlane(tlo, l);
            r += (kj > k) ? 1u : 0u;
        }
    }
    if (idx < (int)M && r < TOPK) topbox[r] = box_per[~(u32)(k & 0xffffffffull)];
}

// Suppression mask, ROW-major: mask[i*32+w] bit jj set iff j=w*64+jj>i, j<TOPK,
// iou>thr. w is block-uniform (topbox[j] broadcast loads).
__global__ __launch_bounds__(256) void k_mask(const float4* __restrict__ topbox,
                                              u64* __restrict__ mask) {
#pragma clang fp contract(off)
    int gid = blockIdx.x * 256 + threadIdx.x;  // 32 * TPAD threads
    int w = gid >> 11, i = gid & (TPAD - 1);
    u64 m = 0;
    int j0 = w << 6;
    if (i < TOPK && j0 + 63 > i) {
        float4 a = topbox[i];
        float aarea = (a.z - a.x) * (a.w - a.y);
        for (int jj = 0; jj < 64; ++jj) {
            int j = j0 + jj;
            if (j < TOPK && j > i) {
                float4 b = topbox[j];
                float barea = (b.z - b.x) * (b.w - b.y);
                float v = iou_pair(a.x, a.y, a.z, a.w, aarea, b.x, b.y, b.z, b.w, barea);
                if (v > NMS_THR) m |= (1ull << jj);
            }
        }
    }
    mask[(size_t)i * 32 + w] = m;
}

// Greedy NMS. Producer/consumer, double-buffered LDS.
// Producers (waves 1-3): FIXED-trip-count unrolled uint4 batch loads ->
// registers -> ds_write. All 6 loads per thread issue before any wait, so a
// chunk costs ~1 memory latency (R4's rolled loop serialized load->ds_write
// at vmcnt(0) per element: 115 cyc/row = latency/ring_depth).
// Consumer (wave 0): recurrence on SALU -- scalar copy (d_lo,d_hi) of removed
// word c; per row ~5 SALU critical ops; vector side ORs whole rows under the
// uniform keep mask. No VALU->readlane->VALU hazard chain.
__global__ __launch_bounds__(256) void k_nms(const u64* __restrict__ mask,
                                             const float4* __restrict__ topbox,
                                             float* __restrict__ out) {
    __shared__ u64 sm[2][64 * 32];  // 2 x 16 KB double buffer
    __shared__ u64 srem[32];
    int t = threadIdx.x;
    int lane = t & 63;
    u32 lw = (u32)(lane & 31);
    u32 rlo = 0, rhi = 0;  // lane w of wave 0 holds removed word w

    // stage chunk 0 (all 256 threads, unrolled batch: 1024 uint4 / 256)
    {
        const uint4* __restrict__ src = (const uint4*)mask;
        uint4 v[4];
#pragma unroll
        for (int k = 0; k < 4; ++k) v[k] = src[t + k * 256];
        uint4* __restrict__ dst = (uint4*)sm[0];
#pragma unroll
        for (int k = 0; k < 4; ++k) dst[t + k * 256] = v[k];
    }
    __syncthreads();

    for (int c = 0; c < 32; ++c) {
        if (t >= 64) {
            if (c + 1 < 32) {
                const uint4* __restrict__ src = (const uint4*)(mask + (size_t)(c + 1) * 2048);
                uint4* __restrict__ dst = (uint4*)sm[(c + 1) & 1];
                int u = t - 64;  // 0..191, six unrolled slots cover 1024 uint4
                uint4 v[6];
#pragma unroll
                for (int k = 0; k < 6; ++k) {
                    int idx = u + k * 192;
                    if (idx < 1024) v[k] = src[idx];
                }
#pragma unroll
                for (int k = 0; k < 6; ++k) {
                    int idx = u + k * 192;
                    if (idx < 1024) dst[idx] = v[k];
                }
            }
        } else {
            const u64* __restrict__ buf = sm[c & 1];
            u32 d_lo = (u32)__builtin_amdgcn_readlane(rlo, c);
            u32 d_hi = (u32)__builtin_amdgcn_readlane(rhi, c);
            u64 ring[8];
#pragma unroll
            for (int p = 0; p < 8; ++p) ring[p] = buf[p * 32 + lw];
#pragma unroll
            for (int l = 0; l < 64; ++l) {
                u64 row = ring[l & 7];
                if (l < 56) ring[l & 7] = buf[(l + 8) * 32 + lw];
                u32 r_lo = (u32)row, r_hi = (u32)(row >> 32);
                u32 sc_lo = (u32)__builtin_amdgcn_readlane(r_lo, c);
                u32 sc_hi = (u32)__builtin_amdgcn_readlane(r_hi, c);
                u32 bit = (l < 32) ? ((d_lo >> l) & 1u) : ((d_hi >> (l - 32)) & 1u);
                u32 mk = bit - 1u;  // keep (bit=0) -> all-ones
                d_lo |= sc_lo & mk;
                d_hi |= sc_hi & mk;
                rlo |= r_lo & mk;
                rhi |= r_hi & mk;
            }
        }
        __syncthreads();
    }
    if (t < 32) srem[t] = ((u64)rhi << 32) | rlo;
    __syncthreads();
    for (int r = t; r < TOPK; r += 256) {
        bool sup = (srem[r >> 6] >> (r & 63)) & 1ull;
        float4 b = topbox[r];
        ((float4*)out)[r] = sup ? make_float4(0.f, 0.f, 0.f, 0.f) : b;
    }
}

extern "C" void kernel_launch(void* const* d_in, const int* in_sizes, int n_in,
                              void* d_out, int out_size, void* d_ws, size_t ws_size,
                              hipStream_t stream) {
    const float* prop = (const float*)d_in[0];
    const float* btp = (const float*)d_in[1];
    const float* cls = (const float*)d_in[2];
    const float* gt = (const float*)d_in[3];
    const int* hptr = (const int*)d_in[4];
    const int* wptr = (const int*)d_in[5];
    float* out = (float*)d_out;
    int N = in_sizes[0] / 4;
    int G = in_sizes[3] / 4;
    if (G > 256) G = 256;

    char* ws = (char*)d_ws;
    size_t o = 0;
    u32* hist = (u32*)(ws + o);       o += (size_t)HBINS * 4;
    u32* csum = (u32*)(ws + o);       o += 1024 * 4;
    u32* meta = (u32*)(ws + o);       o += 256;
    u32* score_bits = (u32*)(ws + o); o += (((size_t)N * 4 + 255) & ~(size_t)255);
    u64* keys = (u64*)(ws + o);       o += (size_t)CAND_CAP * 8;
    float4* box_per = (float4*)(ws + o); o += (size_t)N * 16;
    float4* topbox = (float4*)(ws + o);  o += (size_t)TPAD * 16;
    u64* mask = (u64*)(ws + o);       o += (size_t)TPAD * 32 * 8;
    (void)o; (void)ws_size; (void)n_in; (void)out_size;

    int nb = (N + 255) / 256;
    k_zero<<<HBINS / 4 / 256, 256, 0, stream>>>(hist, meta);
    k_main<<<nb, 256, 0, stream>>>(prop, btp, cls, gt, hptr, wptr, out, box_per, score_bits,
                                   hist, N, G);
    k_hsum<<<1024, 256, 0, stream>>>(hist, csum);
    k_scan2<<<1, 1024, 0, stream>>>(csum, hist, meta);
    k_compact<<<nb, 256, 0, stream>>>(score_bits, meta, meta + 1, keys, N);
    k_rank<<<CAND_CAP / 256, 256, 0, stream>>>(keys, meta, box_per, topbox);
    k_mask<<<(32 * TPAD) / 256, 256, 0, stream>>>(topbox, mask);
    k_nms<<<1, 256, 0, stream>>>(mask, topbox, out);
}

// Round 6
// 307.062 us; speedup vs baseline: 1.0872x; 1.0459x over previous
//
#include <hip/hip_runtime.h>
#include <cstdint>

#define TOPK 2000
#define NMS_THR 0.5f
#define NCLS 21
#define HSHIFT 14
#define HBINS (1u << 18)
#define CAND_CAP 4096
#define TPAD 2048

typedef unsigned long long u64;
typedef unsigned int u32;

// IoU exactly as reference get_iou. contract(off) to match numpy rounding.
__device__ __forceinline__ float iou_pair(float ax1, float ay1, float ax2, float ay2, float aarea,
                                          float bx1, float by1, float bx2, float by2, float barea) {
#pragma clang fp contract(off)
    float ltx = fmaxf(ax1, bx1), lty = fmaxf(ay1, by1);
    float rbx = fminf(ax2, bx2), rby = fminf(ay2, by2);
    float wx = fmaxf(rbx - ltx, 0.f), wy = fmaxf(rby - lty, 0.f);
    float inter = wx * wy;
    return inter / (aarea + barea - inter);
}

__global__ void k_zero(u32* __restrict__ hist, u32* __restrict__ meta) {
    int i = blockIdx.x * 256 + threadIdx.x;
    ((uint4*)hist)[i] = make_uint4(0u, 0u, 0u, 0u);
    if (i < 64) meta[i] = 0u;
}

// Per-proposal: softmax score+cls, decode selected-class box (clamped),
// score bits + histogram, GT IoU argmax (4x unrolled, first-max tree),
// encode reg targets -> out rows 2000+.
// No e[21] array (expf recomputed in compare loop -- identical op sequence to
// reference) => peak VGPR ~45, 8 waves/SIMD to hide the btp gather latency.
__global__ __launch_bounds__(256, 8) void k_main(
    const float* __restrict__ prop, const float* __restrict__ btp,
    const float* __restrict__ cls, const float* __restrict__ gt,
    const int* __restrict__ hptr, const int* __restrict__ wptr,
    float* __restrict__ out, float4* __restrict__ box_per,
    u32* __restrict__ score_bits, u32* __restrict__ hist,
    int N, int G) {
#pragma clang fp contract(off)
    __shared__ float4 sgt[256];
    __shared__ float sga[256];
    int tid = threadIdx.x;
    for (int g = tid; g < G; g += 256) {
        float4 gb = ((const float4*)gt)[g];
        sgt[g] = gb;
        sga[g] = (gb.z - gb.x) * (gb.w - gb.y);
    }
    __syncthreads();

    int i = blockIdx.x * 256 + tid;
    if (i >= N) return;

    float W = (float)wptr[0], H = (float)hptr[0];
    float4 p = ((const float4*)prop)[i];
    float pw = p.z - p.x, ph = p.w - p.y;
    float pcx = p.x + 0.5f * pw, pcy = p.y + 0.5f * ph;

    float s[NCLS];
    const float* crow = cls + (size_t)i * NCLS;
#pragma unroll
    for (int c = 0; c < NCLS; ++c) s[c] = crow[c];

    float m = s[0];
#pragma unroll
    for (int c = 1; c < NCLS; ++c) m = fmaxf(m, s[c]);
    float Z = 0.f;
#pragma unroll
    for (int c = 0; c < NCLS; ++c) Z += expf(s[c] - m);
    float best = -1.f;
    int bc = 1;
#pragma unroll
    for (int c = 1; c < NCLS; ++c) {
        float pr = expf(s[c] - m) / Z;
        if (pr > best) { best = pr; bc = c; }
    }

    float4 t = ((const float4*)btp)[(size_t)i * NCLS + bc];
    float qcx = t.x * pw + pcx, qcy = t.y * ph + pcy;
    float qw = expf(t.z) * pw, qh = expf(t.w) * ph;
    float bx1 = fminf(fmaxf(qcx - 0.5f * qw, 0.f), W);
    float by1 = fminf(fmaxf(qcy - 0.5f * qh, 0.f), H);
    float bx2 = fminf(fmaxf(qcx + 0.5f * qw, 0.f), W);
    float by2 = fminf(fmaxf(qcy + 0.5f * qh, 0.f), H);
    box_per[i] = make_float4(bx1, by1, bx2, by2);

    u32 b = __float_as_uint(best);
    score_bits[i] = b;
    atomicAdd(&hist[b >> HSHIFT], 1u);

    // GT IoU argmax, 4x unrolled with first-max combine tree (left preference,
    // strict >) -- result bit-identical to the sequential scan.
    float parea = pw * ph;
    float bestiou = -1.f;
    int bi = 0;
    int g = 0;
    for (; g + 4 <= G; g += 4) {
        float4 g0 = sgt[g], g1 = sgt[g + 1], g2 = sgt[g + 2], g3 = sgt[g + 3];
        float v0 = iou_pair(g0.x, g0.y, g0.z, g0.w, sga[g], p.x, p.y, p.z, p.w, parea);
        float v1 = iou_pair(g1.x, g1.y, g1.z, g1.w, sga[g + 1], p.x, p.y, p.z, p.w, parea);
        float v2 = iou_pair(g2.x, g2.y, g2.z, g2.w, sga[g + 2], p.x, p.y, p.z, p.w, parea);
        float v3 = iou_pair(g3.x, g3.y, g3.z, g3.w, sga[g + 3], p.x, p.y, p.z, p.w, parea);
        float va = v0; int ia = g;
        if (v1 > va) { va = v1; ia = g + 1; }
        float vb = v2; int ib = g + 2;
        if (v3 > vb) { vb = v3; ib = g + 3; }
        if (vb > va) { va = vb; ia = ib; }
        if (va > bestiou) { bestiou = va; bi = ia; }
    }
    for (; g < G; ++g) {
        float4 gb = sgt[g];
        float v = iou_pair(gb.x, gb.y, gb.z, gb.w, sga[g], p.x, p.y, p.z, p.w, parea);
        if (v > bestiou) { bestiou = v; bi = g; }
    }
    float4 mg = sgt[bi];
    float gw = mg.z - mg.x, gh = mg.w - mg.y;
    float gcx = mg.x + 0.5f * gw, gcy = mg.y + 0.5f * gh;
    float4 rt = make_float4((gcx - pcx) / pw, (gcy - pcy) / ph, logf(gw / pw), logf(gh / ph));
    ((float4*)out)[TOPK + i] = rt;
}

// 1024 blocks x 256: coalesced per-256-bin chunk sums.
__global__ __launch_bounds__(256) void k_hsum(const u32* __restrict__ hist,
                                              u32* __restrict__ csum) {
    int b = blockIdx.x, t = threadIdx.x;
    u32 v = hist[(size_t)b * 256 + t];
#pragma unroll
    for (int o = 32; o; o >>= 1) v += __shfl_xor(v, o);
    __shared__ u32 ps[4];
    if ((t & 63) == 0) ps[t >> 6] = v;
    __syncthreads();
    if (t == 0) csum[b] = ps[0] + ps[1] + ps[2] + ps[3];
}

// One small block: suffix-scan chunk sums, then the winning 256-bin chunk.
__global__ __launch_bounds__(1024) void k_scan2(const u32* __restrict__ csum,
                                                const u32* __restrict__ hist,
                                                u32* __restrict__ meta) {
    __shared__ u32 S[1024];
    __shared__ u32 sh_tc, sh_E;
    int t = threadIdx.x;
    u32 acc = csum[t];
    S[t] = acc;
    __syncthreads();
    for (int off = 1; off < 1024; off <<= 1) {
        u32 v = (t + off < 1024) ? S[t + off] : 0u;
        __syncthreads();
        S[t] += v;
        __syncthreads();
    }
    u32 suff = S[t];
    u32 E = suff - acc;
    if (suff >= TOPK && E < TOPK) { sh_tc = (u32)t; sh_E = E; }
    __syncthreads();
    u32 tc = sh_tc, E0 = sh_E;
    u32 h = (t < 256) ? hist[(size_t)tc * 256 + t] : 0u;
    __syncthreads();
    S[t] = (t < 256) ? h : 0u;
    __syncthreads();
    for (int off = 1; off < 256; off <<= 1) {
        u32 v = (t + off < 1024) ? S[t + off] : 0u;
        __syncthreads();
        S[t] += v;
        __syncthreads();
    }
    if (t < 256) {
        u32 tot = E0 + S[t];
        if (tot >= TOPK && (tot - h) < TOPK) meta[0] = tc * 256u + (u32)t;
    }
}

__global__ __launch_bounds__(256) void k_compact(const u32* __restrict__ score_bits,
                                                 const u32* __restrict__ meta, u32* __restrict__ cnt,
                                                 u64* __restrict__ keys, int N) {
    int i = blockIdx.x * 256 + threadIdx.x;
    if (i >= N) return;
    u32 b = score_bits[i];
    if ((b >> HSHIFT) >= meta[0]) {
        u32 pos = atomicAdd(cnt, 1u);
        if (pos < CAND_CAP) keys[pos] = ((u64)b << 32) | (u32)(~(u32)i);
    }
}

// Rank-sort, 16 blocks. Tile keys 64-at-a-time; broadcast via v_readlane.
// Keys unique -> ranks form a permutation; exact lax.top_k order.
__global__ __launch_bounds__(256) void k_rank(const u64* __restrict__ keys,
                                              const u32* __restrict__ meta,
                                              const float4* __restrict__ box_per,
                                              float4* __restrict__ topbox) {
    __shared__ u64 sk[CAND_CAP];
    int t = threadIdx.x;
    u32 M = meta[1];
    if (M > CAND_CAP) M = CAND_CAP;
    u32 Mp = (M + 63u) & ~63u;
    for (int u = t; u < (int)Mp; u += 256) sk[u] = (u < (int)M) ? keys[u] : 0ull;
    __syncthreads();
    int idx = blockIdx.x * 256 + t;
    u64 k = (idx < (int)M) ? sk[idx] : ~0ull;
    u32 r = 0;
    int lane = t & 63;
    for (int j0 = 0; j0 < (int)Mp; j0 += 64) {
        u64 tv = sk[j0 + lane];
        u32 tlo = (u32)tv, thi = (u32)(tv >> 32);
#pragma unroll
        for (int l = 0; l < 64; ++l) {
            u64 kj = ((u64)(u32)__builtin_amdgcn_readlane(thi, l) << 32) |
                     (u64)(u32)__builtin_amdgcn_readlane(tlo, l);
            r += (kj > k) ? 1u : 0u;
        }
    }
    if (idx < (int)M && r < TOPK) topbox[r] = box_per[~(u32)(k & 0xffffffffull)];
}

// Suppression mask, ROW-major: mask[i*32+w] bit jj set iff j=w*64+jj>i, j<TOPK,
// iou>thr. w is block-uniform (topbox[j] broadcast loads).
__global__ __launch_bounds__(256) void k_mask(const float4* __restrict__ topbox,
                                              u64* __restrict__ mask) {
#pragma clang fp contract(off)
    int gid = blockIdx.x * 256 + threadIdx.x;  // 32 * TPAD threads
    int w = gid >> 11, i = gid & (TPAD - 1);
    u64 m = 0;
    int j0 = w << 6;
    if (i < TOPK && j0 + 63 > i) {
        float4 a = topbox[i];
        float aarea = (a.z - a.x) * (a.w - a.y);
        for (int jj = 0; jj < 64; ++jj) {
            int j = j0 + jj;
            if (j < TOPK && j > i) {
                float4 b = topbox[j];
                float barea = (b.z - b.x) * (b.w - b.y);
                float v = iou_pair(a.x, a.y, a.z, a.w, aarea, b.x, b.y, b.z, b.w, barea);
                if (v > NMS_THR) m |= (1ull << jj);
            }
        }
    }
    mask[(size_t)i * 32 + w] = m;
}

// Greedy NMS. Producer/consumer, double-buffered LDS.
// Producers (waves 1-2, 128 threads): 8 UNCONDITIONAL uint4 loads each
// (exactly 1024 uint4 = 16 KB, no guards -> compiler keeps all 8 in flight,
// one latency per chunk; R5's guarded 6-slot batch serialized at ~6
// latencies/chunk = 5.7k cyc). Consumer (wave 0): recurrence on SALU.
__global__ __launch_bounds__(256) void k_nms(const u64* __restrict__ mask,
                                             const float4* __restrict__ topbox,
                                             float* __restrict__ out) {
    __shared__ u64 sm[2][64 * 32];  // 2 x 16 KB double buffer
    __shared__ u64 srem[32];
    int t = threadIdx.x;
    int lane = t & 63;
    u32 lw = (u32)(lane & 31);
    u32 rlo = 0, rhi = 0;  // lane w of wave 0 holds removed word w

    // stage chunk 0: all 256 threads, 4 unconditional uint4 each
    {
        const uint4* __restrict__ src = (const uint4*)mask;
        uint4 v0 = src[t], v1 = src[t + 256], v2 = src[t + 512], v3 = src[t + 768];
        uint4* __restrict__ dst = (uint4*)sm[0];
        dst[t] = v0; dst[t + 256] = v1; dst[t + 512] = v2; dst[t + 768] = v3;
    }
    __syncthreads();

    for (int c = 0; c < 32; ++c) {
        if (t >= 64 && t < 192) {
            if (c + 1 < 32) {
                const uint4* __restrict__ src = (const uint4*)(mask + (size_t)(c + 1) * 2048);
                uint4* __restrict__ dst = (uint4*)sm[(c + 1) & 1];
                int u = t - 64;  // 0..127; 8 unconditional slots cover 1024 uint4
                uint4 v0 = src[u];
                uint4 v1 = src[u + 128];
                uint4 v2 = src[u + 256];
                uint4 v3 = src[u + 384];
                uint4 v4 = src[u + 512];
                uint4 v5 = src[u + 640];
                uint4 v6 = src[u + 768];
                uint4 v7 = src[u + 896];
                dst[u] = v0;
                dst[u + 128] = v1;
                dst[u + 256] = v2;
                dst[u + 384] = v3;
                dst[u + 512] = v4;
                dst[u + 640] = v5;
                dst[u + 768] = v6;
                dst[u + 896] = v7;
            }
        } else if (t < 64) {
            const u64* __restrict__ buf = sm[c & 1];
            u32 d_lo = (u32)__builtin_amdgcn_readlane(rlo, c);
            u32 d_hi = (u32)__builtin_amdgcn_readlane(rhi, c);
            u64 ring[8];
#pragma unroll
            for (int p = 0; p < 8; ++p) ring[p] = buf[p * 32 + lw];
#pragma unroll
            for (int l = 0; l < 64; ++l) {
                u64 row = ring[l & 7];
                if (l < 56) ring[l & 7] = buf[(l + 8) * 32 + lw];
                u32 r_lo = (u32)row, r_hi = (u32)(row >> 32);
                u32 sc_lo = (u32)__builtin_amdgcn_readlane(r_lo, c);
                u32 sc_hi = (u32)__builtin_amdgcn_readlane(r_hi, c);
                u32 bit = (l < 32) ? ((d_lo >> l) & 1u) : ((d_hi >> (l - 32)) & 1u);
                u32 mk = bit - 1u;  // keep (bit=0) -> all-ones
                d_lo |= sc_lo & mk;
                d_hi |= sc_hi & mk;
                rlo |= r_lo & mk;
                rhi |= r_hi & mk;
            }
        }
        __syncthreads();
    }
    if (t < 32) srem[t] = ((u64)rhi << 32) | rlo;
    __syncthreads();
    for (int r = t; r < TOPK; r += 256) {
        bool sup = (srem[r >> 6] >> (r & 63)) & 1ull;
        float4 b = topbox[r];
        ((float4*)out)[r] = sup ? make_float4(0.f, 0.f, 0.f, 0.f) : b;
    }
}

extern "C" void kernel_launch(void* const* d_in, const int* in_sizes, int n_in,
                              void* d_out, int out_size, void* d_ws, size_t ws_size,
                              hipStream_t stream) {
    const float* prop = (const float*)d_in[0];
    const float* btp = (const float*)d_in[1];
    const float* cls = (const float*)d_in[2];
    const float* gt = (const float*)d_in[3];
    const int* hptr = (const int*)d_in[4];
    const int* wptr = (const int*)d_in[5];
    float* out = (float*)d_out;
    int N = in_sizes[0] / 4;
    int G = in_sizes[3] / 4;
    if (G > 256) G = 256;

    char* ws = (char*)d_ws;
    size_t o = 0;
    u32* hist = (u32*)(ws + o);       o += (size_t)HBINS * 4;
    u32* csum = (u32*)(ws + o);       o += 1024 * 4;
    u32* meta = (u32*)(ws + o);       o += 256;
    u32* score_bits = (u32*)(ws + o); o += (((size_t)N * 4 + 255) & ~(size_t)255);
    u64* keys = (u64*)(ws + o);       o += (size_t)CAND_CAP * 8;
    float4* box_per = (float4*)(ws + o); o += (size_t)N * 16;
    float4* topbox = (float4*)(ws + o);  o += (size_t)TPAD * 16;
    u64* mask = (u64*)(ws + o);       o += (size_t)TPAD * 32 * 8;
    (void)o; (void)ws_size; (void)n_in; (void)out_size;

    int nb = (N + 255) / 256;
    k_zero<<<HBINS / 4 / 256, 256, 0, stream>>>(hist, meta);
    k_main<<<nb, 256, 0, stream>>>(prop, btp, cls, gt, hptr, wptr, out, box_per, score_bits,
                                   hist, N, G);
    k_hsum<<<1024, 256, 0, stream>>>(hist, csum);
    k_scan2<<<1, 1024, 0, stream>>>(csum, hist, meta);
    k_compact<<<nb, 256, 0, stream>>>(score_bits, meta, meta + 1, keys, N);
    k_rank<<<CAND_CAP / 256, 256, 0, stream>>>(keys, meta, box_per, topbox);
    k_mask<<<(32 * TPAD) / 256, 256, 0, stream>>>(topbox, mask);
    k_nms<<<1, 256, 0, stream>>>(mask, topbox, out);
}